// Round 3
// baseline (923.708 us; speedup 1.0000x reference)
//
#include <hip/hip_runtime.h>
#include <hip/hip_bf16.h>

#define H 32
#define DCT 32             // timesteps staged per chunk
#define BT 32              // batch rows per block
#define HPADB 80           // h_lds row stride in bytes (32 bf16 = 64B + 16B pad)
#define XLDS_BYTES (DCT*32*16)
#define HLDS_OFF XLDS_BYTES
#define SMEM_BYTES (XLDS_BYTES + 32*HPADB)

typedef __attribute__((ext_vector_type(8))) short bfrag;
typedef __attribute__((ext_vector_type(4))) float ffrag;

__device__ __forceinline__ unsigned short f2bf(float f) {
  union { float f; unsigned u; } v; v.f = f;
  unsigned r = v.u + 0x7FFFu + ((v.u >> 16) & 1u);   // round-to-nearest-even
  return (unsigned short)(r >> 16);
}

__device__ __forceinline__ float sigmoid_f(float x) {
  float e = __builtin_amdgcn_exp2f(x * -1.44269504f);   // e^-x
  return __builtin_amdgcn_rcpf(1.0f + e);
}
__device__ __forceinline__ float tanh_f(float x) {
  float e = __builtin_amdgcn_exp2f(x * 2.88539008f);    // e^(2x); inf-safe at both ends
  return 1.0f - 2.0f * __builtin_amdgcn_rcpf(e + 1.0f);
}

__global__ __launch_bounds__(256, 2) void lstm_kernel(
    const float* __restrict__ x, const int* __restrict__ mat_idx,
    const int* __restrict__ freq_idx, const float* __restrict__ W_ih,
    const float* __restrict__ W_hh, const float* __restrict__ b_ih,
    const float* __restrict__ b_hh, const float* __restrict__ mat_emb,
    const float* __restrict__ freq_emb, const float* __restrict__ fc_w,
    const float* __restrict__ fc_b, float* __restrict__ out, int T)
{
  __shared__ __align__(16) unsigned char smem[SMEM_BYTES];
  const int tid  = threadIdx.x;
  const int lane = tid & 63;
  const int wid  = tid >> 6;
  const int mtile = wid & 1;      // which 16 batch rows
  const int h16   = wid >> 1;     // which 16 hidden units
  const int q    = lane >> 4;     // k-quad: k0 = q*8
  const int c16  = lane & 15;
  const int hid  = h16*16 + c16;  // hidden unit owned in-register
  const int b0   = blockIdx.x * BT;

  // zero LDS (h0 = 0; x pad slots k=4..7 stay 0 forever)
  for (int i = tid; i < SMEM_BYTES/4; i += 256) ((unsigned*)smem)[i] = 0u;

  // ---- preload W fragments (constant over T) ----
  // B-frag layout: lane l holds B[k = (l>>4)*8 + j][col = l&15]
  // gate g (i,f,g,o) -> col = g*32 + hid
  bfrag fw[4]; bfrag fx[4];
  #pragma unroll
  for (int g = 0; g < 4; ++g) {
    const int col = g*32 + hid;
    const float* wr = W_hh + col*H + q*8;
    #pragma unroll
    for (int j = 0; j < 8; ++j) fw[g][j] = (short)f2bf(wr[j]);
    #pragma unroll
    for (int j = 0; j < 8; ++j) {
      float v = 0.0f;
      if (q == 0) {                       // only k<8 rows of [W_ih; bsum] nonzero
        if (j < 3)       v = W_ih[col*3 + j];
        else if (j == 3) v = b_ih[col] + b_hh[col];
      }
      fx[g][j] = (short)f2bf(v);
    }
  }

  // A-frag read address for h (lane l reads A[row=l&15][k=(l>>4)*8 ..+7])
  const unsigned h_rd = HLDS_OFF + (unsigned)(mtile*16 + c16)*HPADB + q*16;
  // x rows are only 8 bf16 (k=0..7); all k-quads read the same valid bytes —
  // k>=8 A-values are finite and multiply the zeroed fx entries -> contribute 0.
  const unsigned x_rd = (unsigned)(mtile*16 + c16)*16;   // + tl*512

  float cc[4] = {0.f,0.f,0.f,0.f};   // cell state, rows mtile*16+q*4+r
  float hh[4] = {0.f,0.f,0.f,0.f};

  const int srow = tid >> 3, ssub = tid & 7;
  const float* xsrc = x + (size_t)(b0 + srow) * (size_t)T * 3;

  for (int t0 = 0; t0 < T; t0 += DCT) {
    __syncthreads();
    // ---- stage x chunk: x_lds[tl][row][8 bf16] = {x0,x1,x2,1.0,0,0,0,0} ----
    {
      const float* p = xsrc + (size_t)(t0 + ssub*4) * 3;
      float v[12];
      #pragma unroll
      for (int u = 0; u < 12; ++u) v[u] = p[u];
      #pragma unroll
      for (int u = 0; u < 4; ++u) {
        unsigned w0 = (unsigned)f2bf(v[u*3+0]) | ((unsigned)f2bf(v[u*3+1]) << 16);
        unsigned w1 = (unsigned)f2bf(v[u*3+2]) | (0x3F80u << 16);
        unsigned* dst = (unsigned*)(smem + (unsigned)((ssub*4+u)*32 + srow)*16);
        dst[0] = w0; dst[1] = w1;
      }
    }
    __syncthreads();

    for (int tl = 0; tl < DCT; ++tl) {
      bfrag ah = *(const bfrag*)(smem + h_rd);
      bfrag ax = *(const bfrag*)(smem + (unsigned)tl*512 + x_rd);
      ffrag acc[4] = {};
      #pragma unroll
      for (int g = 0; g < 4; ++g) {
        acc[g] = __builtin_amdgcn_mfma_f32_16x16x32_bf16(ax, fx[g], acc[g], 0,0,0);
        acc[g] = __builtin_amdgcn_mfma_f32_16x16x32_bf16(ah, fw[g], acc[g], 0,0,0);
      }
      __syncthreads();   // all h reads done before overwrite
      // D layout: row = (l>>4)*4 + r (+mtile*16), col = l&15 -> (row, hid) in-lane
      #pragma unroll
      for (int r = 0; r < 4; ++r) {
        float ig = sigmoid_f(acc[0][r]);
        float fg = sigmoid_f(acc[1][r]);
        float gg = tanh_f(acc[2][r]);
        float og = sigmoid_f(acc[3][r]);
        float c  = fg*cc[r] + ig*gg;
        cc[r] = c;
        float h = og * tanh_f(c);
        hh[r] = h;
        *(unsigned short*)(smem + HLDS_OFF +
            (unsigned)(mtile*16 + q*4 + r)*HPADB + (unsigned)hid*2) = f2bf(h);
      }
      __syncthreads();   // new h visible
    }
  }

  // ---- epilogue: out[b] = h·fc_w[0:32] + emb terms + fc_b ----
  __syncthreads();
  float* hout = (float*)smem;   // reuse x_lds region as [32][32] f32
  #pragma unroll
  for (int r = 0; r < 4; ++r)
    hout[(mtile*16 + q*4 + r)*H + hid] = hh[r];
  __syncthreads();
  if (tid < BT) {
    const int b = b0 + tid;
    float acc = fc_b[0];
    const float* hv = hout + tid*H;
    #pragma unroll
    for (int k = 0; k < H; ++k) acc += hv[k]*fc_w[k];
    const int mi = mat_idx[b];
    #pragma unroll
    for (int e = 0; e < 4; ++e) acc += mat_emb[mi*4+e]*fc_w[H+e];
    const int fi = freq_idx[b];
    #pragma unroll
    for (int e = 0; e < 2; ++e) acc += freq_emb[fi*2+e]*fc_w[H+4+e];
    out[b] = acc;
  }
}

extern "C" void kernel_launch(void* const* d_in, const int* in_sizes, int n_in,
                              void* d_out, int out_size, void* d_ws, size_t ws_size,
                              hipStream_t stream) {
  const float* x        = (const float*)d_in[0];
  const int*   mat_idx  = (const int*)d_in[1];
  const int*   freq_idx = (const int*)d_in[2];
  const float* W_ih     = (const float*)d_in[3];
  const float* W_hh     = (const float*)d_in[4];
  const float* b_ih     = (const float*)d_in[5];
  const float* b_hh     = (const float*)d_in[6];
  const float* mat_emb  = (const float*)d_in[7];
  const float* freq_emb = (const float*)d_in[8];
  const float* fc_w     = (const float*)d_in[9];
  const float* fc_b     = (const float*)d_in[10];
  float* out = (float*)d_out;
  const int B = in_sizes[1];
  const int T = in_sizes[0] / (B * 3);
  dim3 grid(B / BT), block(256);
  hipLaunchKernelGGL(lstm_kernel, grid, block, 0, stream,
                     x, mat_idx, freq_idx, W_ih, W_hh, b_ih, b_hh,
                     mat_emb, freq_emb, fc_w, fc_b, out, T);
}

// Round 4
// 889.430 us; speedup vs baseline: 1.0385x; 1.0385x over previous
//
#include <hip/hip_runtime.h>
#include <hip/hip_bf16.h>

#define H 32
#define DCT 32               // timesteps staged per chunk
#define BT 16                // batch rows per block
#define HPADB 80             // h row stride bytes (32 bf16 + 16B pad, 16B-aligned)
#define XLDS_BYTES (DCT*BT*16)
#define HLDS_OFF XLDS_BYTES
#define HBUF (BT*HPADB)
#define SMEM_BYTES (XLDS_BYTES + 2*HBUF)

typedef __attribute__((ext_vector_type(8))) short bfrag;
typedef __attribute__((ext_vector_type(4))) float ffrag;

__device__ __forceinline__ unsigned short f2bf(float f) {   // RNE, cold paths only
  union { float f; unsigned u; } v; v.f = f;
  unsigned r = v.u + 0x7FFFu + ((v.u >> 16) & 1u);
  return (unsigned short)(r >> 16);
}

// args pre-scaled by -log2e (sigmoid) / +2log2e (tanh) — scale folded into weights
__device__ __forceinline__ float sig_pre(float s) {
  return __builtin_amdgcn_rcpf(1.0f + __builtin_amdgcn_exp2f(s));
}
__device__ __forceinline__ float tanh_pre(float s) {
  return 1.0f - 2.0f * __builtin_amdgcn_rcpf(1.0f + __builtin_amdgcn_exp2f(s));
}

__device__ __forceinline__ void lstm_step(unsigned char* smem,
    unsigned x_off, unsigned rd_off, unsigned wr_off,
    const bfrag* fx, const bfrag* fw, ffrag fzero, float* cc, float* hh)
{
  bfrag ah = *(const bfrag*)(smem + rd_off);
  bfrag ax = *(const bfrag*)(smem + x_off);
  ffrag a0 = __builtin_amdgcn_mfma_f32_16x16x32_bf16(ax, fx[0], fzero, 0,0,0);
  ffrag a1 = __builtin_amdgcn_mfma_f32_16x16x32_bf16(ax, fx[1], fzero, 0,0,0);
  ffrag a2 = __builtin_amdgcn_mfma_f32_16x16x32_bf16(ax, fx[2], fzero, 0,0,0);
  ffrag a3 = __builtin_amdgcn_mfma_f32_16x16x32_bf16(ax, fx[3], fzero, 0,0,0);
  a0 = __builtin_amdgcn_mfma_f32_16x16x32_bf16(ah, fw[0], a0, 0,0,0);
  a1 = __builtin_amdgcn_mfma_f32_16x16x32_bf16(ah, fw[1], a1, 0,0,0);
  a2 = __builtin_amdgcn_mfma_f32_16x16x32_bf16(ah, fw[2], a2, 0,0,0);
  a3 = __builtin_amdgcn_mfma_f32_16x16x32_bf16(ah, fw[3], a3, 0,0,0);
  // D layout: row = q*4 + r, col = c16 -> (row, hid) in-lane
  #pragma unroll
  for (int r = 0; r < 4; ++r) {
    float i_ = sig_pre(a0[r]);
    float f_ = sig_pre(a1[r]);
    float tg = tanh_pre(a2[r]);
    float o_ = sig_pre(a3[r]);
    float c  = f_*cc[r] + i_*tg;
    cc[r] = c;
    float h = o_ * tanh_pre(c * 2.885390082f);
    hh[r] = h;
    __hip_bfloat16 hb = __float2bfloat16(h);
    *(unsigned short*)(smem + wr_off + (unsigned)r*HPADB) =
        __builtin_bit_cast(unsigned short, hb);
  }
  __syncthreads();   // new h visible; WAR on read-buffer safe (reads precede this)
}

__global__ __launch_bounds__(128, 2) void lstm_kernel(
    const float* __restrict__ x, const int* __restrict__ mat_idx,
    const int* __restrict__ freq_idx, const float* __restrict__ W_ih,
    const float* __restrict__ W_hh, const float* __restrict__ b_ih,
    const float* __restrict__ b_hh, const float* __restrict__ mat_emb,
    const float* __restrict__ freq_emb, const float* __restrict__ fc_w,
    const float* __restrict__ fc_b, float* __restrict__ out, int T)
{
  __shared__ __align__(16) unsigned char smem[SMEM_BYTES];
  const int tid  = threadIdx.x;
  const int lane = tid & 63;
  const int h16  = tid >> 6;       // 0..1: which 16 hidden units
  const int q    = lane >> 4;      // k-quad
  const int c16  = lane & 15;
  const int hid  = h16*16 + c16;
  const int b0   = blockIdx.x * BT;

  // zero LDS (h0 = 0; x pad slots k=4..7 stay 0 forever)
  for (int i = tid; i < SMEM_BYTES/4; i += 128) ((unsigned*)smem)[i] = 0u;

  // ---- preload W fragments, activation scale folded in ----
  // B-frag: lane l holds B[k=(l>>4)*8+j][col=l&15]; gate g -> col = g*32+hid
  bfrag fw[4]; bfrag fx[4];
  #pragma unroll
  for (int g = 0; g < 4; ++g) {
    const float sc = (g == 2) ? 2.885390082f : -1.442695041f;  // g-gate: tanh
    const int col = g*H + hid;
    const float* wr = W_hh + col*H + q*8;
    #pragma unroll
    for (int j = 0; j < 8; ++j) fw[g][j] = (short)f2bf(wr[j] * sc);
    #pragma unroll
    for (int j = 0; j < 8; ++j) {
      float v = 0.0f;
      if (q == 0) {                 // only k<8 rows of [W_ih; bsum] nonzero
        if (j < 3)       v = W_ih[col*3 + j] * sc;
        else if (j == 3) v = (b_ih[col] + b_hh[col]) * sc;
      }
      fx[g][j] = (short)f2bf(v);
    }
  }

  // h double-buffer offsets (A/B), A-frag read: row=c16, k-quad q
  const unsigned rdA = HLDS_OFF + (unsigned)c16*HPADB + (unsigned)q*16;
  const unsigned rdB = rdA + HBUF;
  const unsigned wrA = HLDS_OFF + (unsigned)(q*4)*HPADB + (unsigned)hid*2;
  const unsigned wrB = wrA + HBUF;
  // x rows are 8 bf16 (k<8); k>=8 A-garbage multiplies zeroed fx -> contributes 0
  const unsigned x_rd = (unsigned)c16*16;

  ffrag fzero = {0.f,0.f,0.f,0.f};
  float cc[4] = {0.f,0.f,0.f,0.f};
  float hh[4] = {0.f,0.f,0.f,0.f};

  const int srow = tid >> 3, ssub = tid & 7;
  const float* xsrc = x + (size_t)(b0 + srow) * (size_t)T * 3;

  __syncthreads();   // zero-init visible before first staging overwrite

  for (int t0 = 0; t0 < T; t0 += DCT) {
    // ---- stage x chunk: x_lds[tl][row][8 bf16] = {x0,x1,x2,1.0, 0,0,0,0} ----
    // (prev chunk's x reads completed at last step's barrier)
    {
      const float* p = xsrc + (size_t)(t0 + ssub*4) * 3;
      float v[12];
      #pragma unroll
      for (int u = 0; u < 12; ++u) v[u] = p[u];
      #pragma unroll
      for (int u = 0; u < 4; ++u) {
        unsigned w0 = (unsigned)f2bf(v[u*3+0]) | ((unsigned)f2bf(v[u*3+1]) << 16);
        unsigned w1 = (unsigned)f2bf(v[u*3+2]) | (0x3F80u << 16);
        uint2* dst = (uint2*)(smem + (unsigned)((ssub*4+u)*BT + srow)*16);
        *dst = make_uint2(w0, w1);
      }
    }
    __syncthreads();

    #pragma unroll 2
    for (int tl = 0; tl < DCT; tl += 2) {   // ping-pong: one barrier per step
      lstm_step(smem, x_rd + (unsigned)tl*(BT*16),     rdA, wrB, fx, fw, fzero, cc, hh);
      lstm_step(smem, x_rd + (unsigned)(tl+1)*(BT*16), rdB, wrA, fx, fw, fzero, cc, hh);
    }
  }

  // ---- epilogue: out[b] = h·fc_w[0:32] + emb terms + fc_b ----
  float* hout = (float*)smem;   // reuse x region as [16][32] f32
  #pragma unroll
  for (int r = 0; r < 4; ++r)
    hout[(q*4 + r)*H + hid] = hh[r];
  __syncthreads();
  if (tid < BT) {
    const int b = b0 + tid;
    float acc = fc_b[0];
    const float* hv = hout + tid*H;
    #pragma unroll
    for (int k = 0; k < H; ++k) acc += hv[k]*fc_w[k];
    const int mi = mat_idx[b];
    #pragma unroll
    for (int e = 0; e < 4; ++e) acc += mat_emb[mi*4+e]*fc_w[H+e];
    const int fi = freq_idx[b];
    #pragma unroll
    for (int e = 0; e < 2; ++e) acc += freq_emb[fi*2+e]*fc_w[H+4+e];
    out[b] = acc;
  }
}

extern "C" void kernel_launch(void* const* d_in, const int* in_sizes, int n_in,
                              void* d_out, int out_size, void* d_ws, size_t ws_size,
                              hipStream_t stream) {
  const float* x        = (const float*)d_in[0];
  const int*   mat_idx  = (const int*)d_in[1];
  const int*   freq_idx = (const int*)d_in[2];
  const float* W_ih     = (const float*)d_in[3];
  const float* W_hh     = (const float*)d_in[4];
  const float* b_ih     = (const float*)d_in[5];
  const float* b_hh     = (const float*)d_in[6];
  const float* mat_emb  = (const float*)d_in[7];
  const float* freq_emb = (const float*)d_in[8];
  const float* fc_w     = (const float*)d_in[9];
  const float* fc_b     = (const float*)d_in[10];
  float* out = (float*)d_out;
  const int B = in_sizes[1];
  const int T = in_sizes[0] / (B * 3);
  dim3 grid(B / BT), block(128);
  hipLaunchKernelGGL(lstm_kernel, grid, block, 0, stream,
                     x, mat_idx, freq_idx, W_ih, W_hh, b_ih, b_hh,
                     mat_emb, freq_emb, fc_w, fc_b, out, T);
}